// Round 7
// baseline (971.656 us; speedup 1.0000x reference)
//
#include <hip/hip_runtime.h>
#include <hip/hip_bf16.h>

// NonlinearReservoirCell: B=262144 rows, M=3 independent tiny MLPs
//   free_water = last_free_water + sum_n runoff
//   a1 = relu(runoff @ W1 + b1)   (256 -> 256)
//   a2 = relu(a1 @ W2 + b2)       (256 -> 128)
//   ratio = sigmoid(a2 @ W3 + b3) (128 -> 1)
//   flow = fw*ratio + last_flow*(1-ratio);  new_fw = fw - flow
// R7: OCCUPANCY experiment. Every prior config ran <=8 waves/CU and all hit
//     ~287 us (latency-bound by Little's law: ~10 KB in flight/CU). This
//     round quarters the per-wave accumulator by splitting h/k2 across the
//     4 waves of a block (acc1 32 VGPR, acc2 16), a1 crosses waves via a
//     16-KB LDS panel (R4's verified conflict-free swizzle), weights stream
//     from L2-resident prep buffers (R6-verified path). VGPR forced <=128,
//     LDS 35 KB -> 4 blocks/CU x 4 waves = 16 waves/CU, 2x all prior rounds.

#define B_TOT 262144
#define M_    3
#define N_    256
#define H1_   256
#define H2_   128
#define BM_   (B_TOT * M_)

typedef __bf16 bf16_t;
typedef __bf16  bf16x8 __attribute__((ext_vector_type(8)));
typedef float   f32x16 __attribute__((ext_vector_type(16)));
typedef float   f32x4  __attribute__((ext_vector_type(4)));

__device__ __forceinline__ unsigned pack_bf2(float lo, float hi) {
  union { bf16_t b; unsigned short u; } a, c;
  a.b = (bf16_t)lo; c.b = (bf16_t)hi;
  return ((unsigned)c.u << 16) | (unsigned)a.u;
}

// ---------------------------------------------------------------------------
// Prep: transpose + cvt weights into per-lane MFMA A-fragment order (bf16).
// w1s[m][kk(16)][t(8)][lane(64)][ii(8)] = bf16(W1[m][n=16kk+8*(lane>>5)+ii][h=32t+(lane&31)])
// w2s[m][kk2(16)][t2(4)][lane(64)][ii(8)] = bf16(W2[m][h=16kk2+8*(lane>>5)+ii][k2=32t2+(lane&31)])
// ---------------------------------------------------------------------------
__global__ __launch_bounds__(256) void prep_weights(
    const float* __restrict__ W1, const float* __restrict__ W2,
    bf16_t* __restrict__ w1s, bf16_t* __restrict__ w2s)
{
  int id = blockIdx.x * 256 + threadIdx.x;
  const int NW1 = M_ * 16 * 8 * 64;   // 24576 groups of 8
  const int NW2 = M_ * 16 * 4 * 64;   // 12288 groups of 8
  if (id < NW1) {
    int lane = id & 63;
    int t    = (id >> 6) & 7;
    int kk   = (id >> 9) & 15;
    int m    = id >> 13;
    int h  = 32 * t + (lane & 31);
    int n0 = 16 * kk + 8 * (lane >> 5);
    bf16x8 v;
#pragma unroll
    for (int ii = 0; ii < 8; ++ii)
      v[ii] = (bf16_t)W1[((size_t)m * N_ + (n0 + ii)) * H1_ + h];
    *reinterpret_cast<bf16x8*>(&w1s[(size_t)id * 8]) = v;
  } else if (id < NW1 + NW2) {
    int j    = id - NW1;
    int lane = j & 63;
    int t2   = (j >> 6) & 3;
    int kk2  = (j >> 8) & 15;
    int m    = j >> 12;
    int k2 = 32 * t2 + (lane & 31);
    int h0 = 16 * kk2 + 8 * (lane >> 5);
    bf16x8 v;
#pragma unroll
    for (int ii = 0; ii < 8; ++ii)
      v[ii] = (bf16_t)W2[((size_t)m * H1_ + (h0 + ii)) * H2_ + k2];
    *reinterpret_cast<bf16x8*>(&w2s[(size_t)j * 8]) = v;
  }
}

// ---------------------------------------------------------------------------
// Main kernel. Block = 256 thr = 4 waves sharing one 32-row unit at a time.
// Wave wv: L1 h-slice [64wv, 64wv+64), L2 k2-slice [32wv, 32wv+32).
// Block owns 8 units (256 rows). grid = 3072 (m = bid%3). 4 blocks/CU.
// ---------------------------------------------------------------------------
__global__ __launch_bounds__(256, 4) void reservoir_kernel(
    const float* __restrict__ last_flow,
    const float* __restrict__ last_fw,
    const float* __restrict__ runoff,
    const float* __restrict__ b1,
    const float* __restrict__ b2,
    const float* __restrict__ W3,
    const float* __restrict__ b3,
    const bf16_t* __restrict__ w1s,
    const bf16_t* __restrict__ w2s,
    float* __restrict__ out)
{
  // [32 rows][256 bf16] panels, 8-B-granule XOR swizzle (R4-verified):
  //   write: phys8 = lane ^ ((row&15)<<1); read 16B granule g: (g^(row&15))*8
  __shared__ alignas(16) bf16_t sR[32 * 256];   // 16 KB runoff panel
  __shared__ alignas(16) bf16_t sY[32 * 256];   // 16 KB a1 panel
  __shared__ alignas(16) float  sB1f[H1_];
  __shared__ alignas(16) float  sB2f[H2_];
  __shared__ alignas(16) float  sW3f[H2_];
  __shared__ alignas(16) float  sPart[4][32];
  __shared__ alignas(16) float  sRsum[32];

  const int tid  = threadIdx.x;
  const int lane = tid & 63;
  const int wv   = tid >> 6;
  const int hi   = lane >> 5;
  const int r    = lane & 31;
  const int r15  = r & 15;

  const int m        = blockIdx.x % 3;
  const size_t rbase = (size_t)(blockIdx.x / 3) * 256;

  const bf16_t* w1base = w1s + (size_t)m * 65536;
  const bf16_t* w2base = w2s + (size_t)m * 32768;
  const float   b3v    = b3[m];

  sB1f[tid] = b1[m * H1_ + tid];
  if (tid < H2_) { sB2f[tid] = b2[m * H2_ + tid]; sW3f[tid] = W3[m * H2_ + tid]; }

  for (int u = 0; u < 8; ++u) {
    // ---- stage: wave stages rows [8wv, 8wv+8) as 1-KB coalesced bursts ----
    {
      const float* src = runoff
          + ((rbase + u * 32 + wv * 8) * M_ + m) * N_ + lane * 4;
#pragma unroll
      for (int j = 0; j < 8; ++j) {
        f32x4 v = *reinterpret_cast<const f32x4*>(src + (size_t)j * (M_ * N_));
        uint2 d;
        d.x = pack_bf2(v[0], v[1]);
        d.y = pack_bf2(v[2], v[3]);
        const int rl = wv * 8 + j;
        const int p8 = lane ^ ((rl & 15) << 1);
        *reinterpret_cast<uint2*>(&sR[rl * 256 + p8 * 4]) = d;
      }
    }
    __syncthreads();   // bar A: sR(u) complete (tables too, first iter)

    // ---- Layer 1: a1^T for h-slice [64wv, 64wv+64) ----
    f32x16 acc1[2] = {f32x16{}, f32x16{}};
    float rsum = 0.f;
#pragma unroll
    for (int kk = 0; kk < 16; ++kk) {
      bf16x8 bf = *reinterpret_cast<const bf16x8*>(
          &sR[r * 256 + (((2 * kk + hi) ^ r15) * 8)]);
      if (wv == 0) {
#pragma unroll
        for (int j = 0; j < 8; ++j) rsum += (float)bf[j];
      }
#pragma unroll
      for (int tl = 0; tl < 2; ++tl) {
        bf16x8 af = *reinterpret_cast<const bf16x8*>(
            w1base + (size_t)kk * 4096 + (2 * wv + tl) * 512 + lane * 8);
        acc1[tl] = __builtin_amdgcn_mfma_f32_32x32x16_bf16(af, bf, acc1[tl], 0, 0, 0);
      }
    }

    // a1 = relu(acc1 + b1) -> sY (aligned 8-B swizzled writes)
#pragma unroll
    for (int tl = 0; tl < 2; ++tl) {
      const int tg = 2 * wv + tl;
#pragma unroll
      for (int g2 = 0; g2 < 4; ++g2) {
        const int hb = 32 * tg + 8 * g2 + 4 * hi;    // lane's 4-run base h
        f32x4 bv = *reinterpret_cast<const f32x4*>(&sB1f[hb]);
        uint2 d;
        d.x = pack_bf2(fmaxf(acc1[tl][4 * g2 + 0] + bv[0], 0.f),
                       fmaxf(acc1[tl][4 * g2 + 1] + bv[1], 0.f));
        d.y = pack_bf2(fmaxf(acc1[tl][4 * g2 + 2] + bv[2], 0.f),
                       fmaxf(acc1[tl][4 * g2 + 3] + bv[3], 0.f));
        const int G = 4 * tg + g2;                   // 16-B granule = h>>3
        *reinterpret_cast<uint2*>(
            &sY[r * 256 + ((G ^ r15) * 8) + hi * 4]) = d;
      }
    }
    if (wv == 0) {
      rsum += __shfl_xor(rsum, 32, 64);
      if (hi == 0) sRsum[r] = rsum;
    }
    __syncthreads();   // bar B: sY(u) + sRsum complete

    // ---- Layer 2: a2^T for k2-slice [32wv, 32wv+32) ----
    f32x16 acc2 = f32x16{};
#pragma unroll
    for (int kk2 = 0; kk2 < 16; ++kk2) {
      bf16x8 bf = *reinterpret_cast<const bf16x8*>(
          &sY[r * 256 + (((2 * kk2 + hi) ^ r15) * 8)]);
      bf16x8 wf = *reinterpret_cast<const bf16x8*>(
          w2base + (size_t)kk2 * 2048 + wv * 512 + lane * 8);
      acc2 = __builtin_amdgcn_mfma_f32_32x32x16_bf16(wf, bf, acc2, 0, 0, 0);
    }

    // ---- Layer 3 partial: relu(a2+b2) . W3 over this wave's k2 slice ----
    float part = 0.f;
#pragma unroll
    for (int e = 0; e < 16; ++e) {
      const int k2 = 32 * wv + (e & 3) + 8 * (e >> 2) + 4 * hi;
      part += fmaxf(acc2[e] + sB2f[k2], 0.f) * sW3f[k2];
    }
    part += __shfl_xor(part, 32, 64);
    if (hi == 0) sPart[wv][r] = part;
    __syncthreads();   // bar C: partials visible

    // ---- epilogue: one thread per row ----
    if (tid < 32) {
      const size_t grow = rbase + u * 32 + tid;
      const size_t oi   = grow * M_ + m;
      const float pt    = sPart[0][tid] + sPart[1][tid] + sPart[2][tid]
                        + sPart[3][tid] + b3v;
      const float ratio = 1.0f / (1.0f + __expf(-pt));
      const float fw    = last_fw[oi] + sRsum[tid];
      const float lf    = last_flow[oi];
      const float flow  = fw * ratio + lf * (1.0f - ratio);
      out[oi]       = fw - flow;   // new_free_water
      out[BM_ + oi] = flow;        // flow
    }
  }
}

// ---------------------------------------------------------------------------
extern "C" void kernel_launch(void* const* d_in, const int* in_sizes, int n_in,
                              void* d_out, int out_size, void* d_ws, size_t ws_size,
                              hipStream_t stream) {
  const float* last_flow = (const float*)d_in[0];
  const float* last_fw   = (const float*)d_in[1];
  const float* runoff    = (const float*)d_in[2];
  const float* W1 = (const float*)d_in[3];
  const float* b1 = (const float*)d_in[4];
  const float* W2 = (const float*)d_in[5];
  const float* b2 = (const float*)d_in[6];
  const float* W3 = (const float*)d_in[7];
  const float* b3 = (const float*)d_in[8];
  float* out = (float*)d_out;

  bf16_t* w1s = (bf16_t*)d_ws;                    // 3*65536 bf16 = 384 KB
  bf16_t* w2s = w1s + (size_t)M_ * 65536;         // 3*32768 bf16 = 192 KB

  prep_weights<<<144, 256, 0, stream>>>(W1, W2, w1s, w2s);

  reservoir_kernel<<<3072, 256, 0, stream>>>(last_flow, last_fw, runoff,
                                             b1, b2, W3, b3, w1s, w2s, out);
}

// Round 8
// 414.366 us; speedup vs baseline: 2.3449x; 2.3449x over previous
//
#include <hip/hip_runtime.h>
#include <hip/hip_bf16.h>

// NonlinearReservoirCell — R8: measurement round.
// Main kernel = exact R5 config (verified 287 us). Appended: a pure-read
// microbench probe (sequential float4 grid-stride sum over the whole 805-MB
// runoff buffer) to decide between:
//   T-C: strided-thirds DRAM pattern limits reads to ~2.8 TB/s (probe ~6 TB/s)
//   T-D: ~2.8 TB/s IS the pure-read ceiling here (probe ~2.8 TB/s)
// Decision read from total dur: ~420-440 us => T-C; ~560-590 us => T-D.

#define B_TOT 262144
#define M_    3
#define N_    256
#define H1_   256
#define H2_   128
#define BM_   (B_TOT * M_)

typedef __bf16 bf16_t;
typedef __bf16  bf16x8 __attribute__((ext_vector_type(8)));
typedef float   f32x16 __attribute__((ext_vector_type(16)));
typedef float   f32x4  __attribute__((ext_vector_type(4)));

__device__ __forceinline__ unsigned pack_bf2(float lo, float hi) {
  union { bf16_t b; unsigned short u; } a, c;
  a.b = (bf16_t)lo; c.b = (bf16_t)hi;
  return ((unsigned)c.u << 16) | (unsigned)a.u;
}

__device__ __forceinline__ void gload_lds16(const void* g, void* l) {
  __builtin_amdgcn_global_load_lds(
      (const __attribute__((address_space(1))) void*)g,
      (__attribute__((address_space(3))) void*)l, 16, 0, 0);
}

// ---------------------------------------------------------------------------
// PROBE: pure sequential read of the full runoff buffer, f32x4 grid-stride.
// 2048 blocks x 256 thr, 96 iters/thread, wave-reduced sink writes (32 KB).
// ---------------------------------------------------------------------------
__global__ __launch_bounds__(256) void probe_seq_read(
    const f32x4* __restrict__ src, float* __restrict__ sink, size_t n4)
{
  size_t i = (size_t)blockIdx.x * 256 + threadIdx.x;
  const size_t stride = (size_t)gridDim.x * 256;
  float s = 0.f;
  for (; i < n4; i += stride) {
    f32x4 v = src[i];
    s += v[0] + v[1] + v[2] + v[3];
  }
#pragma unroll
  for (int o = 32; o; o >>= 1) s += __shfl_down(s, o, 64);
  if ((threadIdx.x & 63) == 0)
    sink[blockIdx.x * 4 + (threadIdx.x >> 6)] = s;
}

// ---------------------------------------------------------------------------
// Prep: transpose + cvt weights into per-lane MFMA A-fragment order (bf16).
// ---------------------------------------------------------------------------
__global__ __launch_bounds__(256) void prep_weights(
    const float* __restrict__ W1, const float* __restrict__ W2,
    bf16_t* __restrict__ w1s, bf16_t* __restrict__ w2s)
{
  int id = blockIdx.x * 256 + threadIdx.x;
  const int NW1 = M_ * 16 * 8 * 64;   // 24576 groups of 8
  const int NW2 = M_ * 16 * 4 * 64;   // 12288 groups of 8
  if (id < NW1) {
    int lane = id & 63;
    int t    = (id >> 6) & 7;
    int kk   = (id >> 9) & 15;
    int m    = id >> 13;
    int h  = 32 * t + (lane & 31);
    int n0 = 16 * kk + 8 * (lane >> 5);
    bf16x8 v;
#pragma unroll
    for (int ii = 0; ii < 8; ++ii)
      v[ii] = (bf16_t)W1[((size_t)m * N_ + (n0 + ii)) * H1_ + h];
    *reinterpret_cast<bf16x8*>(&w1s[(size_t)id * 8]) = v;
  } else if (id < NW1 + NW2) {
    int j    = id - NW1;
    int lane = j & 63;
    int t2   = (j >> 6) & 3;
    int kk2  = (j >> 8) & 15;
    int m    = j >> 12;
    int k2 = 32 * t2 + (lane & 31);
    int h0 = 16 * kk2 + 8 * (lane >> 5);
    bf16x8 v;
#pragma unroll
    for (int ii = 0; ii < 8; ++ii)
      v[ii] = (bf16_t)W2[((size_t)m * H1_ + (h0 + ii)) * H2_ + k2];
    *reinterpret_cast<bf16x8*>(&w2s[(size_t)j * 8]) = v;
  }
}

// ---------------------------------------------------------------------------
// Main fused kernel — EXACT R5 (287 us verified). Block = 4 waves; wave owns
// 32 batch rows. grid = 6144 1D; m = bid%3, chunk = bid/3.
// ---------------------------------------------------------------------------
__global__ __launch_bounds__(256, 2) void reservoir_kernel(
    const float* __restrict__ last_flow,
    const float* __restrict__ last_fw,
    const float* __restrict__ runoff,
    const float* __restrict__ b1,
    const float* __restrict__ b2,
    const float* __restrict__ W3,
    const float* __restrict__ b3,
    const bf16_t* __restrict__ w1s,
    const bf16_t* __restrict__ w2s,
    float* __restrict__ out)
{
  __shared__ alignas(16) float  sR[2][128 * 32];   // 2 x 16 KB
  __shared__ alignas(16) bf16_t sW1[2][8192];      // 2 x 16 KB (2 kk-panels)
  __shared__ alignas(16) bf16_t sW2[2][2048];      // 2 x 4 KB
  __shared__ alignas(16) float  sB1[H1_];
  __shared__ alignas(16) float  sB2[H2_];
  __shared__ alignas(16) float  sW3[H2_];

  const int tid  = threadIdx.x;
  const int lane = tid & 63;
  const int wv   = tid >> 6;
  const int hi   = lane >> 5;
  const int r    = lane & 31;
  const int r7   = r & 7;

  const int bidx  = blockIdx.x;        // 0..6143
  const int m     = bidx % 3;
  const int chunk = bidx / 3;          // 0..2047
  const int row0  = chunk * 128;
  const int row   = row0 + wv * 32 + r;

  const int l3 = lane >> 3;          // row within 8-row slab
  const int gsw = (lane & 7) ^ l3;   // logical granule feeding phys slot lane&7

  const bf16_t* w1base = w1s + (size_t)m * 65536;
  const bf16_t* w2base = w2s + (size_t)m * 32768;

  auto stage_R = [&](int g, int buf) {     // panel g: cols 32g..32g+31
#pragma unroll
    for (int c = 0; c < 4; ++c) {
      int slab = wv * 4 + c;               // 16 slabs of 8 rows
      const float* src = runoff
          + ((size_t)(row0 + slab * 8 + l3) * M_ + m) * N_ + 32 * g + 4 * gsw;
      gload_lds16(src, &sR[buf][slab * 256]);
    }
  };
  auto stage_w1g = [&](int g, int buf) {   // panels 2g,2g+1: 16 KB
#pragma unroll
    for (int c = 0; c < 4; ++c) {
      int chnk = wv * 4 + c;               // 16 chunks of 1 KB
      gload_lds16(w1base + (size_t)g * 8192 + chnk * 512 + lane * 8,
                  &sW1[buf][chnk * 512]);
    }
  };
  auto stage_w2 = [&](int kk2, int buf) {
    gload_lds16(w2base + (size_t)kk2 * 2048 + wv * 512 + lane * 8,
                &sW2[buf][wv * 512]);
  };

  sB1[tid] = b1[m * H1_ + tid];
  if (tid < H2_) { sB2[tid] = b2[m * H2_ + tid]; sW3[tid] = W3[m * H2_ + tid]; }
  stage_R(0, 0);
  stage_w1g(0, 0);
  __syncthreads();

  // ---------------- Layer 1: a1^T[h][r] ----------------
  f32x16 acc1[8];
#pragma unroll
  for (int t = 0; t < 8; ++t) {
#pragma unroll
    for (int g2 = 0; g2 < 4; ++g2) {
      f32x4 bv = *reinterpret_cast<const f32x4*>(&sB1[32 * t + 8 * g2 + 4 * hi]);
      acc1[t][4 * g2 + 0] = bv[0];
      acc1[t][4 * g2 + 1] = bv[1];
      acc1[t][4 * g2 + 2] = bv[2];
      acc1[t][4 * g2 + 3] = bv[3];
    }
  }

  float rsum = 0.f;

#pragma unroll
  for (int g = 0; g < 8; ++g) {
    const int cb = g & 1;
    if (g < 7) { stage_R(g + 1, cb ^ 1); stage_w1g(g + 1, cb ^ 1); }
    else       { stage_w2(0, 0); }   // prefetch first W2 panel

#pragma unroll
    for (int q = 0; q < 2; ++q) {    // kk = 2g + q
      const float* rb = &sR[cb][(wv * 32 + r) * 32];
      f32x4 qa = *reinterpret_cast<const f32x4*>(&rb[((4 * q + 2 * hi + 0) ^ r7) * 4]);
      f32x4 qb = *reinterpret_cast<const f32x4*>(&rb[((4 * q + 2 * hi + 1) ^ r7) * 4]);
      rsum += qa[0] + qa[1] + qa[2] + qa[3] + qb[0] + qb[1] + qb[2] + qb[3];
      bf16x8 bfrag;
      bfrag[0] = (bf16_t)qa[0]; bfrag[1] = (bf16_t)qa[1];
      bfrag[2] = (bf16_t)qa[2]; bfrag[3] = (bf16_t)qa[3];
      bfrag[4] = (bf16_t)qb[0]; bfrag[5] = (bf16_t)qb[1];
      bfrag[6] = (bf16_t)qb[2]; bfrag[7] = (bf16_t)qb[3];

#pragma unroll
      for (int t = 0; t < 8; ++t) {
        bf16x8 afrag = *reinterpret_cast<const bf16x8*>(
            &sW1[cb][q * 4096 + t * 512 + lane * 8]);
        acc1[t] = __builtin_amdgcn_mfma_f32_32x32x16_bf16(afrag, bfrag, acc1[t], 0, 0, 0);
      }
    }
    __syncthreads();
  }

  // -------- inter-layer: relu + bf16 pack --------
  unsigned P[8][2][2][2];
#pragma unroll
  for (int t = 0; t < 8; ++t)
#pragma unroll
    for (int q = 0; q < 2; ++q)
#pragma unroll
      for (int v = 0; v < 2; ++v)
#pragma unroll
        for (int s = 0; s < 2; ++s) {
          int e = 8 * q + 4 * v + 2 * s;
          P[t][q][v][s] = pack_bf2(fmaxf(acc1[t][e], 0.f),
                                   fmaxf(acc1[t][e + 1], 0.f));
        }

  // ---------------- Layer 2: a2^T[k2][r] ----------------
  f32x16 acc2[4];
#pragma unroll
  for (int t2 = 0; t2 < 4; ++t2) {
#pragma unroll
    for (int g2 = 0; g2 < 4; ++g2) {
      f32x4 bv = *reinterpret_cast<const f32x4*>(&sB2[32 * t2 + 8 * g2 + 4 * hi]);
      acc2[t2][4 * g2 + 0] = bv[0];
      acc2[t2][4 * g2 + 1] = bv[1];
      acc2[t2][4 * g2 + 2] = bv[2];
      acc2[t2][4 * g2 + 3] = bv[3];
    }
  }

#pragma unroll
  for (int kk2 = 0; kk2 < 16; ++kk2) {
    const int cb = kk2 & 1;
    if (kk2 < 15) stage_w2(kk2 + 1, cb ^ 1);
    const int t = kk2 >> 1, q = kk2 & 1;

    auto r0 = __builtin_amdgcn_permlane32_swap(P[t][q][0][0], P[t][q][1][0], false, false);
    auto r1 = __builtin_amdgcn_permlane32_swap(P[t][q][0][1], P[t][q][1][1], false, false);
    union { unsigned u[4]; bf16x8 v; } bb;
    bb.u[0] = r0[0]; bb.u[1] = r1[0]; bb.u[2] = r0[1]; bb.u[3] = r1[1];

#pragma unroll
    for (int t2 = 0; t2 < 4; ++t2) {
      bf16x8 afrag = *reinterpret_cast<const bf16x8*>(
          &sW2[cb][t2 * 512 + lane * 8]);
      acc2[t2] = __builtin_amdgcn_mfma_f32_32x32x16_bf16(afrag, bb.v, acc2[t2], 0, 0, 0);
    }
    __syncthreads();
  }

  // ---------------- Layer 3: dot with W3, sigmoid, blend ----------------
  float part = 0.f;
#pragma unroll
  for (int t2 = 0; t2 < 4; ++t2) {
#pragma unroll
    for (int g2 = 0; g2 < 4; ++g2) {
      f32x4 w3v = *reinterpret_cast<const f32x4*>(&sW3[32 * t2 + 8 * g2 + 4 * hi]);
      part += fmaxf(acc2[t2][4 * g2 + 0], 0.f) * w3v[0]
            + fmaxf(acc2[t2][4 * g2 + 1], 0.f) * w3v[1]
            + fmaxf(acc2[t2][4 * g2 + 2], 0.f) * w3v[2]
            + fmaxf(acc2[t2][4 * g2 + 3], 0.f) * w3v[3];
    }
  }
  part += __shfl_xor(part, 32, 64);  // combine k2-mod-8 halves
  rsum += __shfl_xor(rsum, 32, 64);  // combine n-mod-16 halves

  const float x     = part + b3[m];
  const float ratio = 1.0f / (1.0f + __expf(-x));
  const size_t oi   = (size_t)row * M_ + m;
  const float fw    = last_fw[oi] + rsum;
  const float lf    = last_flow[oi];
  const float flow  = fw * ratio + lf * (1.0f - ratio);
  if (hi == 0) {
    out[oi]        = fw - flow;   // new_free_water
    out[BM_ + oi]  = flow;        // flow
  }
}

// ---------------------------------------------------------------------------
extern "C" void kernel_launch(void* const* d_in, const int* in_sizes, int n_in,
                              void* d_out, int out_size, void* d_ws, size_t ws_size,
                              hipStream_t stream) {
  const float* last_flow = (const float*)d_in[0];
  const float* last_fw   = (const float*)d_in[1];
  const float* runoff    = (const float*)d_in[2];
  const float* W1 = (const float*)d_in[3];
  const float* b1 = (const float*)d_in[4];
  const float* W2 = (const float*)d_in[5];
  const float* b2 = (const float*)d_in[6];
  const float* W3 = (const float*)d_in[7];
  const float* b3 = (const float*)d_in[8];
  float* out = (float*)d_out;

  bf16_t* w1s = (bf16_t*)d_ws;                    // 3*65536 bf16 = 384 KB
  bf16_t* w2s = w1s + (size_t)M_ * 65536;         // 3*32768 bf16 = 192 KB
  float*  sink = (float*)((char*)d_ws + (1 << 20));  // probe sink, 32 KB @1MB

  prep_weights<<<144, 256, 0, stream>>>(W1, W2, w1s, w2s);

  reservoir_kernel<<<6144, 256, 0, stream>>>(last_flow, last_fw, runoff,
                                             b1, b2, W3, b3, w1s, w2s, out);

  // pure-read BW probe over the full runoff buffer (805 MB)
  const size_t n4 = (size_t)BM_ * N_ / 4;   // 50,331,648 f32x4
  probe_seq_read<<<2048, 256, 0, stream>>>(
      reinterpret_cast<const f32x4*>(runoff), sink, n4);
}

// Round 9
// 341.307 us; speedup vs baseline: 2.8469x; 1.2141x over previous
//
#include <hip/hip_runtime.h>
#include <hip/hip_bf16.h>

// NonlinearReservoirCell: B=262144 rows, M=3 independent tiny MLPs
//   free_water = last_free_water + sum_n runoff
//   a1 = relu(runoff @ W1 + b1)   (256 -> 256)
//   a2 = relu(a1 @ W2 + b2)       (256 -> 128)
//   ratio = sigmoid(a2 @ W3 + b3) (128 -> 1)
//   flow = fw*ratio + last_flow*(1-ratio);  new_fw = fw - flow
// R9: DENSE-ROW redesign (R8 probe: sequential read 6.6 TB/s vs 2.8 for the
//     per-m thirds pattern -> pattern was the wall). Block owns 512 rows and
//     processes ALL 3 m's: per 32-row unit, stage full 3-KB rows (96 KB
//     contiguous, nontemporal) -> bf16 swizzled LDS panel -> 3 m-passes
//     (R7-verified compute: h-split waves, sY cross-wave panel, register
//     W1/W2 slices from L2-resident prep buffer). 2 blocks/CU, 66 KB LDS.

#define B_TOT 262144
#define M_    3
#define N_    256
#define H1_   256
#define H2_   128
#define BM_   (B_TOT * M_)
#define ROWS_BLK 512
#define UNITS    16

typedef __bf16 bf16_t;
typedef __bf16  bf16x8 __attribute__((ext_vector_type(8)));
typedef float   f32x16 __attribute__((ext_vector_type(16)));
typedef float   f32x4  __attribute__((ext_vector_type(4)));

__device__ __forceinline__ unsigned pack_bf2(float lo, float hi) {
  union { bf16_t b; unsigned short u; } a, c;
  a.b = (bf16_t)lo; c.b = (bf16_t)hi;
  return ((unsigned)c.u << 16) | (unsigned)a.u;
}

// ---------------------------------------------------------------------------
// Prep: transpose + cvt weights into per-lane MFMA A-fragment order (bf16).
// w1s[m][kk(16)][t(8)][lane(64)][ii(8)] = bf16(W1[m][n=16kk+8*(lane>>5)+ii][h=32t+(lane&31)])
// w2s[m][kk2(16)][t2(4)][lane(64)][ii(8)] = bf16(W2[m][h=16kk2+8*(lane>>5)+ii][k2=32t2+(lane&31)])
// ---------------------------------------------------------------------------
__global__ __launch_bounds__(256) void prep_weights(
    const float* __restrict__ W1, const float* __restrict__ W2,
    bf16_t* __restrict__ w1s, bf16_t* __restrict__ w2s)
{
  int id = blockIdx.x * 256 + threadIdx.x;
  const int NW1 = M_ * 16 * 8 * 64;   // 24576 groups of 8
  const int NW2 = M_ * 16 * 4 * 64;   // 12288 groups of 8
  if (id < NW1) {
    int lane = id & 63;
    int t    = (id >> 6) & 7;
    int kk   = (id >> 9) & 15;
    int m    = id >> 13;
    int h  = 32 * t + (lane & 31);
    int n0 = 16 * kk + 8 * (lane >> 5);
    bf16x8 v;
#pragma unroll
    for (int ii = 0; ii < 8; ++ii)
      v[ii] = (bf16_t)W1[((size_t)m * N_ + (n0 + ii)) * H1_ + h];
    *reinterpret_cast<bf16x8*>(&w1s[(size_t)id * 8]) = v;
  } else if (id < NW1 + NW2) {
    int j    = id - NW1;
    int lane = j & 63;
    int t2   = (j >> 6) & 3;
    int kk2  = (j >> 8) & 15;
    int m    = j >> 12;
    int k2 = 32 * t2 + (lane & 31);
    int h0 = 16 * kk2 + 8 * (lane >> 5);
    bf16x8 v;
#pragma unroll
    for (int ii = 0; ii < 8; ++ii)
      v[ii] = (bf16_t)W2[((size_t)m * H1_ + (h0 + ii)) * H2_ + k2];
    *reinterpret_cast<bf16x8*>(&w2s[(size_t)j * 8]) = v;
  }
}

// ---------------------------------------------------------------------------
// Main kernel. grid = 512, block = 4 waves, 2 blocks/CU. Block owns 512 rows,
// 16 units of 32 rows x all 3 m. Wave wv: L1 h-slice [64wv,64wv+64),
// L2 k2-slice [32wv,32wv+32).
// ---------------------------------------------------------------------------
__global__ __launch_bounds__(256, 2) void reservoir_kernel(
    const float* __restrict__ last_flow,
    const float* __restrict__ last_fw,
    const float* __restrict__ runoff,
    const float* __restrict__ b1,
    const float* __restrict__ b2,
    const float* __restrict__ W3,
    const float* __restrict__ b3,
    const bf16_t* __restrict__ w1s,
    const bf16_t* __restrict__ w2s,
    float* __restrict__ out)
{
  // sXP: [32 rows][768 bf16] (full 3-KB rows as bf16). 16-B granules,
  // phys = mgroup*32 + (j ^ row), j = granule-in-mgroup. 48 KB.
  __shared__ alignas(16) bf16_t sXP[32 * 768];
  // sY: [32 rows][256 bf16] a1 panel, R7-verified swizzle. 16 KB.
  __shared__ alignas(16) bf16_t sY[32 * 256];
  __shared__ float sPart[M_][4][32];
  __shared__ float sRsum[M_][32];

  const int tid  = threadIdx.x;
  const int lane = tid & 63;
  const int wv   = tid >> 6;
  const int hi   = lane >> 5;
  const int r    = lane & 31;
  const int r15  = r & 15;

  const size_t rbase = (size_t)blockIdx.x * ROWS_BLK;

  for (int u = 0; u < UNITS; ++u) {
    // ---- stage: 32 full rows = 96 KB contiguous, nontemporal ----
    {
      const float* src = runoff + (rbase + u * 32) * (M_ * N_);
#pragma unroll
      for (int c = 0; c < 12; ++c) {
        const int s   = c * 256 + tid;        // 32-B chunk index in [0,3072)
        const int row = s / 96;               // 96 chunks per 3-KB row
        const int c32 = s - row * 96;
        f32x4 va = __builtin_nontemporal_load(
            reinterpret_cast<const f32x4*>(src + (size_t)s * 8));
        f32x4 vb = __builtin_nontemporal_load(
            reinterpret_cast<const f32x4*>(src + (size_t)s * 8 + 4));
        uint4 d;
        d.x = pack_bf2(va[0], va[1]);
        d.y = pack_bf2(va[2], va[3]);
        d.z = pack_bf2(vb[0], vb[1]);
        d.w = pack_bf2(vb[2], vb[3]);
        const int mg   = c32 >> 5;
        const int j    = c32 & 31;
        const int phys = mg * 32 + (j ^ row);
        *reinterpret_cast<uint4*>(&sXP[row * 768 + phys * 8]) = d;
      }
    }
    __syncthreads();   // bar S: panel(u) ready

    for (int m = 0; m < M_; ++m) {
      const bf16_t* w1m = w1s + (size_t)m * 65536;
      const bf16_t* w2m = w2s + (size_t)m * 32768;

      // ---------------- Layer 1: h-slice [64wv, 64wv+64) ----------------
      f32x16 a0 = f32x16{}, a1m = f32x16{};
      float rs = 0.f;
#pragma unroll
      for (int half = 0; half < 2; ++half) {
        bf16x8 wf[8][2];
#pragma unroll
        for (int k = 0; k < 8; ++k)
#pragma unroll
          for (int tl = 0; tl < 2; ++tl)
            wf[k][tl] = *reinterpret_cast<const bf16x8*>(
                w1m + (size_t)(half * 8 + k) * 4096 + (2 * wv + tl) * 512 + lane * 8);
#pragma unroll
        for (int k = 0; k < 8; ++k) {
          const int kk = half * 8 + k;
          const int j  = 2 * kk + hi;
          bf16x8 bf = *reinterpret_cast<const bf16x8*>(
              &sXP[r * 768 + (m * 32 + (j ^ r)) * 8]);
          if (wv == m) {
#pragma unroll
            for (int i = 0; i < 8; ++i) rs += (float)bf[i];
          }
          a0  = __builtin_amdgcn_mfma_f32_32x32x16_bf16(wf[k][0], bf, a0, 0, 0, 0);
          a1m = __builtin_amdgcn_mfma_f32_32x32x16_bf16(wf[k][1], bf, a1m, 0, 0, 0);
        }
      }
      if (wv == m) {
        rs += __shfl_xor(rs, 32, 64);
        if (hi == 0) sRsum[m][r] = rs;
      }

      // a1 = relu(acc + b1) -> sY (R7-verified mapping & swizzle)
      const float* b1m = b1 + m * H1_;
#pragma unroll
      for (int tl = 0; tl < 2; ++tl) {
        const int tg = 2 * wv + tl;
        const f32x16& ac = (tl == 0) ? a0 : a1m;
#pragma unroll
        for (int g2 = 0; g2 < 4; ++g2) {
          const int hb = 32 * tg + 8 * g2 + 4 * hi;
          f32x4 bv = *reinterpret_cast<const f32x4*>(&b1m[hb]);
          uint2 d;
          d.x = pack_bf2(fmaxf(ac[4 * g2 + 0] + bv[0], 0.f),
                         fmaxf(ac[4 * g2 + 1] + bv[1], 0.f));
          d.y = pack_bf2(fmaxf(ac[4 * g2 + 2] + bv[2], 0.f),
                         fmaxf(ac[4 * g2 + 3] + bv[3], 0.f));
          const int G = 4 * tg + g2;
          *reinterpret_cast<uint2*>(
              &sY[r * 256 + ((G ^ r15) * 8) + hi * 4]) = d;
        }
      }
      __syncthreads();   // bar Y1: sY complete

      // ---------------- Layer 2: k2-slice [32wv, 32wv+32) ----------------
      bf16x8 w2f[16];
#pragma unroll
      for (int kk2 = 0; kk2 < 16; ++kk2)
        w2f[kk2] = *reinterpret_cast<const bf16x8*>(
            w2m + (size_t)kk2 * 2048 + wv * 512 + lane * 8);
      f32x16 c2 = f32x16{};
#pragma unroll
      for (int kk2 = 0; kk2 < 16; ++kk2) {
        bf16x8 bf = *reinterpret_cast<const bf16x8*>(
            &sY[r * 256 + (((2 * kk2 + hi) ^ r15) * 8)]);
        c2 = __builtin_amdgcn_mfma_f32_32x32x16_bf16(w2f[kk2], bf, c2, 0, 0, 0);
      }

      // ---------------- Layer 3 partial ----------------
      const float* b2m = b2 + m * H2_;
      const float* w3m = W3 + m * H2_;
      float part = 0.f;
#pragma unroll
      for (int e = 0; e < 16; ++e) {
        const int k2 = 32 * wv + (e & 3) + 8 * (e >> 2) + 4 * hi;
        part += fmaxf(c2[e] + b2m[k2], 0.f) * w3m[k2];
      }
      part += __shfl_xor(part, 32, 64);
      if (hi == 0) sPart[m][wv][r] = part;
      __syncthreads();   // bar Y2: partials + rsum visible

      // ---------------- epilogue: one thread per row ----------------
      if (tid < 32) {
        const size_t grow = rbase + u * 32 + tid;
        const size_t oi   = grow * M_ + m;
        const float pt    = sPart[m][0][tid] + sPart[m][1][tid]
                          + sPart[m][2][tid] + sPart[m][3][tid] + b3[m];
        const float ratio = 1.0f / (1.0f + __expf(-pt));
        const float fw    = last_fw[oi] + sRsum[m][tid];
        const float lf    = last_flow[oi];
        const float flow  = fw * ratio + lf * (1.0f - ratio);
        out[oi]       = fw - flow;   // new_free_water
        out[BM_ + oi] = flow;        // flow
      }
    }
  }
}

// ---------------------------------------------------------------------------
extern "C" void kernel_launch(void* const* d_in, const int* in_sizes, int n_in,
                              void* d_out, int out_size, void* d_ws, size_t ws_size,
                              hipStream_t stream) {
  const float* last_flow = (const float*)d_in[0];
  const float* last_fw   = (const float*)d_in[1];
  const float* runoff    = (const float*)d_in[2];
  const float* W1 = (const float*)d_in[3];
  const float* b1 = (const float*)d_in[4];
  const float* W2 = (const float*)d_in[5];
  const float* b2 = (const float*)d_in[6];
  const float* W3 = (const float*)d_in[7];
  const float* b3 = (const float*)d_in[8];
  float* out = (float*)d_out;

  bf16_t* w1s = (bf16_t*)d_ws;                    // 3*65536 bf16 = 384 KB
  bf16_t* w2s = w1s + (size_t)M_ * 65536;         // 3*32768 bf16 = 192 KB

  prep_weights<<<144, 256, 0, stream>>>(W1, W2, w1s, w2s);

  reservoir_kernel<<<B_TOT / ROWS_BLK, 256, 0, stream>>>(
      last_flow, last_fw, runoff, b1, b2, W3, b3, w1s, w2s, out);
}